// Round 8
// baseline (1276.350 us; speedup 1.0000x reference)
//
#include <hip/hip_runtime.h>
#include <stdint.h>

typedef unsigned short u16;
typedef unsigned int u32;
typedef __attribute__((ext_vector_type(4))) float f32x4;
typedef __attribute__((ext_vector_type(8))) short bf16x8;

#define NN 32768
#define EE 524288
#define DD 384
#define NREL 8
#define NGR 128
#define KREL (NREL * DD)  // 3072

__device__ __forceinline__ float bf2f(u16 u) {
  union { u32 u; float f; } v; v.u = ((u32)u) << 16; return v.f;
}
__device__ __forceinline__ u16 f2bf(float f) {
  union { float f; u32 u; } v; v.f = f;
  u32 r = v.u + 0x7fffu + ((v.u >> 16) & 1u);
  return (u16)(r >> 16);
}
__device__ __forceinline__ float2 up2(u32 p) {
  return make_float2(bf2f((u16)(p & 0xffffu)), bf2f((u16)(p >> 16)));
}
__device__ __forceinline__ u32 pk2(float a, float b) {
  return (u32)f2bf(a) | ((u32)f2bf(b) << 16);
}
// async 16B global->LDS (LDS dest = wave-uniform base + lane*16)
__device__ __forceinline__ void gl16(const u16* g, char* s) {
  __builtin_amdgcn_global_load_lds(
      (const __attribute__((address_space(1))) unsigned int*)(const void*)g,
      (__attribute__((address_space(3))) unsigned int*)(void*)s, 16, 0, 0);
}
__device__ __forceinline__ float dot4(uint4 a, uint4 b) {
  float2 p, q; float acc;
  p = up2(a.x); q = up2(b.x); acc  = p.x * q.x + p.y * q.y;
  p = up2(a.y); q = up2(b.y); acc += p.x * q.x + p.y * q.y;
  p = up2(a.z); q = up2(b.z); acc += p.x * q.x + p.y * q.y;
  p = up2(a.w); q = up2(b.w); acc += p.x * q.x + p.y * q.y;
  return acc;
}

// ---- per-node: invn = 1/|x|, H = bf16(x) ; zero cur ----
__global__ __launch_bounds__(256) void k_invnorm(const float* __restrict__ x,
                                                 float* __restrict__ invn,
                                                 u16* __restrict__ h0,
                                                 int* __restrict__ cur) {
  const int gid = blockIdx.x * 256 + threadIdx.x;
  if (gid < NN) cur[gid] = 0;
  const int node = gid >> 6;
  const int l = threadIdx.x & 63;
  const float* row = x + (size_t)node * DD;
  float v[6];
  float s = 0.f;
#pragma unroll
  for (int j = 0; j < 6; ++j) { v[j] = row[l + 64 * j]; s += v[j] * v[j]; }
#pragma unroll
  for (int off = 32; off > 0; off >>= 1) s += __shfl_xor(s, off, 64);
  if (l == 0) invn[node] = rsqrtf(s);
  u16* hr = h0 + (size_t)node * DD;
#pragma unroll
  for (int j = 0; j < 6; ++j) hr[l + 64 * j] = f2bf(v[j]);
}

// ---- weight transpose + bf16 convert ----
// WcatT[n][k] (384 x 3072) = W_rel flat[k*384 + n]
// W2T[j][k]   (384 x 768)  = k<384 ? W_mp[k][j] : W_self[k-384][j]
__global__ void k_prepW(const float* __restrict__ Wrel, const float* __restrict__ Wmp,
                        const float* __restrict__ Wself,
                        u16* __restrict__ WcatT, u16* __restrict__ W2T) {
  const int i = blockIdx.x * 256 + threadIdx.x;
  const int total1 = DD * KREL;
  const int total2 = DD * 768;
  if (i < total1) {
    const int n = i / KREL, k = i % KREL;
    WcatT[i] = f2bf(Wrel[(size_t)k * DD + n]);
  } else if (i < total1 + total2) {
    const int ii = i - total1;
    const int j = ii / 768, k = ii % 768;
    const float v = (k < DD) ? Wmp[k * DD + j] : Wself[(k - DD) * DD + j];
    W2T[ii] = f2bf(v);
  }
}

// ---- per-edge weight: 16 lanes/edge + fused hist ----
__global__ __launch_bounds__(256) void k_cos(const u16* __restrict__ H,
                                             const float* __restrict__ invn,
                                             const int* __restrict__ ei,
                                             const int* __restrict__ ety,
                                             const float* __restrict__ ncs,
                                             float* __restrict__ we,
                                             int* __restrict__ cnt) {
  const int e = (int)((blockIdx.x * 256 + threadIdx.x) >> 4);
  const int sub = threadIdx.x & 15;
  const int s = ei[e], d = ei[EE + e];
  const uint4* rs = (const uint4*)(H + (size_t)s * DD);
  const uint4* rd = (const uint4*)(H + (size_t)d * DD);
  float acc = 0.f;
#pragma unroll
  for (int j = 0; j < 3; ++j) acc += dot4(rs[sub + 16 * j], rd[sub + 16 * j]);
#pragma unroll
  for (int m = 1; m < 16; m <<= 1) acc += __shfl_xor(acc, m, 64);
  if (sub == 0) {
    we[e] = acc * invn[s] * invn[d] / ncs[ety[e]];
    atomicAdd(&cnt[d], 1);
  }
}

// single block, 1024 threads: exclusive scan of 32768 degrees
__global__ __launch_bounds__(1024) void k_scan(const int* __restrict__ deg,
                                               int* __restrict__ rp,
                                               int* __restrict__ cur) {
  __shared__ int ps[1024];
  const int t = threadIdx.x;
  const int base = t * 32;
  int loc[32];
  int tot = 0;
#pragma unroll
  for (int j = 0; j < 32; ++j) { loc[j] = tot; tot += deg[base + j]; }
  ps[t] = tot;
  __syncthreads();
  for (int off = 1; off < 1024; off <<= 1) {
    const int v = (t >= off) ? ps[t - off] : 0;
    __syncthreads();
    ps[t] += v;
    __syncthreads();
  }
  const int myoff = ps[t] - tot;  // exclusive
#pragma unroll
  for (int j = 0; j < 32; ++j) {
    const int val = myoff + loc[j];
    rp[base + j] = val;
    cur[base + j] = val;
  }
  if (t == 1023) rp[NN] = EE;
}

__global__ void k_scatter(const int* __restrict__ ei, const int* __restrict__ etype,
                          const float* __restrict__ we, int* __restrict__ cur,
                          int* __restrict__ epack, float* __restrict__ wsort) {
  const int e = blockIdx.x * 256 + threadIdx.x;
  const int d = ei[EE + e];
  const int pos = atomicAdd(&cur[d], 1);
  epack[pos] = ei[e] | (etype[e] << 16);
  wsort[pos] = we[e];
}

// ---- relation-aware aggregation for nodes [base, base+gridDim) ----
__global__ __launch_bounds__(192) void k_edge_rel(
    const u16* __restrict__ H, const int* __restrict__ rp,
    const int* __restrict__ epack, const float* __restrict__ wsort,
    u16* __restrict__ agg, float* __restrict__ sbuf, int base) {
  const int i = base + blockIdx.x;
  const int t = threadIdx.x;
  const int e0 = rp[i], e1 = rp[i + 1];
  float2 a0 = {0, 0}, a1 = {0, 0}, a2 = {0, 0}, a3 = {0, 0};
  float2 a4 = {0, 0}, a5 = {0, 0}, a6 = {0, 0}, a7 = {0, 0};
  float s0 = 0, s1 = 0, s2 = 0, s3 = 0, s4 = 0, s5 = 0, s6 = 0, s7 = 0;
  for (int e = e0; e < e1; ++e) {
    const int pk = epack[e];
    const float w = wsort[e];
    const int src = pk & 0xffff;
    const int ty = pk >> 16;
    const float2 hv = up2(*(const u32*)(H + (size_t)src * DD + 2 * t));
    const float vx = w * hv.x, vy = w * hv.y;
    switch (ty) {
      case 0: a0.x += vx; a0.y += vy; if (t == 0) s0 += w; break;
      case 1: a1.x += vx; a1.y += vy; if (t == 0) s1 += w; break;
      case 2: a2.x += vx; a2.y += vy; if (t == 0) s2 += w; break;
      case 3: a3.x += vx; a3.y += vy; if (t == 0) s3 += w; break;
      case 4: a4.x += vx; a4.y += vy; if (t == 0) s4 += w; break;
      case 5: a5.x += vx; a5.y += vy; if (t == 0) s5 += w; break;
      case 6: a6.x += vx; a6.y += vy; if (t == 0) s6 += w; break;
      default: a7.x += vx; a7.y += vy; if (t == 0) s7 += w; break;
    }
  }
  u32* ap = (u32*)(agg + (size_t)blockIdx.x * KREL);
  ap[0 * 192 + t] = pk2(a0.x, a0.y);
  ap[1 * 192 + t] = pk2(a1.x, a1.y);
  ap[2 * 192 + t] = pk2(a2.x, a2.y);
  ap[3 * 192 + t] = pk2(a3.x, a3.y);
  ap[4 * 192 + t] = pk2(a4.x, a4.y);
  ap[5 * 192 + t] = pk2(a5.x, a5.y);
  ap[6 * 192 + t] = pk2(a6.x, a6.y);
  ap[7 * 192 + t] = pk2(a7.x, a7.y);
  if (t == 0) {
    float* sp = sbuf + (size_t)i * 8;
    sp[0] = s0; sp[1] = s1; sp[2] = s2; sp[3] = s3;
    sp[4] = s4; sp[5] = s5; sp[6] = s6; sp[7] = s7;
  }
}

// ---- unweighted gather-sum: smp[i] = sum_e H2[src] ----
__global__ __launch_bounds__(192) void k_edge_sum(
    const u16* __restrict__ H2, const int* __restrict__ rp,
    const int* __restrict__ epack, u16* __restrict__ smp) {
  const int i = blockIdx.x, t = threadIdx.x;
  const int e0 = rp[i], e1 = rp[i + 1];
  float ax = 0.f, ay = 0.f;
  for (int e = e0; e < e1; ++e) {
    const int src = epack[e] & 0xffff;
    const float2 hv = up2(*(const u32*)(H2 + (size_t)src * DD + 2 * t));
    ax += hv.x; ay += hv.y;
  }
  *(u32*)(smp + (size_t)i * DD + 2 * t) = pk2(ax, ay);
}

// ---- bf16 MFMA GEMM v3: M-tile=32, FULL N=384 per block, 256 thr / 4 waves.
// A read exactly once (no col-split); B is an L2-resident broadcast.
// LDS 52KB = A[32][64] (4KB) + B[384][64] (48KB) as 52 1KB slabs; wave w
// stages slabs w+4j (13 gl16). Pre-swizzled source XOR (R7-verified, 0 confl).
// Wave w computes col quarter [w*96, w*96+96), acc[2][6].
// MODE 0: K=3072, A=A0 (agg chunk rows); o = bf16(relu(C + s@b_rel))
// MODE 1: K=768,  A=[A0=smp | A1=H2] (stride 384, split k=384), rows global;
//         o = bf16(relu(C + deg*b_mp + b_self))
template <int MODE>
__global__ __launch_bounds__(256) void k_gemm(
    const u16* __restrict__ A0, const u16* __restrict__ A1,
    const u16* __restrict__ Bt, u16* __restrict__ o_bf,
    const float* __restrict__ sbuf, const float* __restrict__ brel,
    const float* __restrict__ bmp, const float* __restrict__ bself,
    const int* __restrict__ rp) {
  constexpr int K = (MODE == 0) ? KREL : 768;
  constexpr int AS = (MODE == 0) ? KREL : DD;  // A row stride
  __shared__ __align__(16) u16 smem[(32 + 384) * 64];  // 52 KB
  const int tid = threadIdx.x;
  const int w = tid >> 6, l = tid & 63;
  const int mb = blockIdx.x * 32;
  const int lsub = l >> 3;                    // row within 8-row slab
  const int swz16 = ((l & 7) ^ lsub) * 8;     // pre-swizzled logical u16 col
  char* const sbase = (char*)smem;
  // compute-side
  const int lr = l & 15;
  const int cb = l >> 4;     // 0..3
  const int sx = l & 7;      // row&7 of every row this lane reads
  f32x4 acc[2][6] = {};
  for (int k0 = 0; k0 < K; k0 += 64) {
    const u16* Ab; int ak;
    if (MODE == 1 && k0 >= DD) { Ab = A1; ak = k0 - DD; }
    else { Ab = A0; ak = k0; }
#pragma unroll
    for (int j = 0; j < 13; ++j) {
      const int s = w + 4 * j;  // 0..51
      char* dst = sbase + s * 1024 + l * 16;
      if (s < 4) {
        gl16(Ab + (size_t)(mb + s * 8 + lsub) * AS + ak + swz16, dst);
      } else {
        gl16(Bt + (size_t)((s - 4) * 8 + lsub) * K + k0 + swz16, dst);
      }
    }
    __syncthreads();
#pragma unroll
    for (int kk = 0; kk < 64; kk += 32) {
      const int cs = (((kk >> 3) + cb) ^ sx) << 4;  // physical byte col
      bf16x8 af[2], bfr[6];
#pragma unroll
      for (int m = 0; m < 2; ++m)
        af[m] = *(const bf16x8*)(sbase + (m * 16 + lr) * 128 + cs);
#pragma unroll
      for (int n = 0; n < 6; ++n)
        bfr[n] = *(const bf16x8*)(sbase + 4096 + (w * 96 + n * 16 + lr) * 128 + cs);
#pragma unroll
      for (int m = 0; m < 2; ++m)
#pragma unroll
        for (int n = 0; n < 6; ++n)
          acc[m][n] = __builtin_amdgcn_mfma_f32_16x16x32_bf16(af[m], bfr[n], acc[m][n], 0, 0, 0);
    }
    __syncthreads();
  }
  const int lg = l >> 4;
#pragma unroll
  for (int n = 0; n < 6; ++n) {
    const int col = w * 96 + n * 16 + lr;
    float bcol[8];
    float bb = 0.f, bs = 0.f;
    if (MODE == 0) {
#pragma unroll
      for (int r = 0; r < 8; ++r) bcol[r] = brel[r * DD + col];
    } else {
      bb = bmp[col];
      bs = bself[col];
    }
#pragma unroll
    for (int m = 0; m < 2; ++m) {
#pragma unroll
      for (int q = 0; q < 4; ++q) {
        const int row = mb + m * 16 + lg * 4 + q;
        float v = acc[m][n][q];
        if (MODE == 0) {
          const float* sp = sbuf + (size_t)row * 8;
          float bias = 0.f;
#pragma unroll
          for (int r = 0; r < 8; ++r) bias += sp[r] * bcol[r];
          v = fmaxf(v + bias, 0.f);
        } else {
          const float deg = (float)(rp[row + 1] - rp[row]);
          v = fmaxf(v + deg * bb + bs, 0.f);
        }
        o_bf[(size_t)row * DD + col] = f2bf(v);
      }
    }
  }
}

// ---- mean over 256 nodes per graph ----
__global__ __launch_bounds__(192) void k_mean(const u16* __restrict__ H,
                                              float* __restrict__ out) {
  const int g = blockIdx.x, t = threadIdx.x;
  float ax = 0.f, ay = 0.f;
  const u16* base = H + (size_t)g * 256 * DD;
  for (int j = 0; j < 256; ++j) {
    const float2 hv = up2(*(const u32*)(base + (size_t)j * DD + 2 * t));
    ax += hv.x; ay += hv.y;
  }
  out[g * DD + 2 * t]     = ax * (1.f / 256.f);
  out[g * DD + 2 * t + 1] = ay * (1.f / 256.f);
}

extern "C" void kernel_launch(void* const* d_in, const int* in_sizes, int n_in,
                              void* d_out, int out_size, void* d_ws, size_t ws_size,
                              hipStream_t stream) {
  const float* x     = (const float*)d_in[0];
  const int*   ei    = (const int*)d_in[1];
  const int*   ety   = (const int*)d_in[2];
  const float* Wrel  = (const float*)d_in[4];
  const float* brel  = (const float*)d_in[5];
  const float* ncs   = (const float*)d_in[6];
  const float* Wmp   = (const float*)d_in[7];
  const float* bmp   = (const float*)d_in[8];
  const float* Wself = (const float*)d_in[9];
  const float* bself = (const float*)d_in[10];
  float* out = (float*)d_out;
  (void)in_sizes; (void)n_in; (void)out_size;

  char* ws = (char*)d_ws;
  size_t off = 0;
  auto alloc = [&](size_t bytes) {
    void* p = ws + off;
    off = (off + bytes + 255) & ~(size_t)255;
    return p;
  };
  float* invn  = (float*)alloc((size_t)NN * 4);
  int*   rp    = (int*)alloc(((size_t)NN + 1) * 4);
  int*   cur   = (int*)alloc((size_t)NN * 4);
  float* sbuf  = (float*)alloc((size_t)NN * 8 * 4);
  float* we    = (float*)alloc((size_t)EE * 4);
  int*   epack = (int*)alloc((size_t)EE * 4);
  float* wsort = (float*)alloc((size_t)EE * 4);
  u16*   WcatT = (u16*)alloc((size_t)DD * KREL * 2);
  u16*   W2T   = (u16*)alloc((size_t)DD * 768 * 2);
  u16*   H     = (u16*)alloc((size_t)NN * DD * 2);
  u16*   H2    = (u16*)alloc((size_t)NN * DD * 2);
  // agg chunk sized adaptively; smp aliased into agg's region when it fits
  size_t remain = (ws_size > off) ? (ws_size - off) : 0;
  int C = NN;
  while (C > 1024 && (size_t)C * KREL * 2 > remain) C >>= 1;
  u16* agg;
  u16* smp;
  if (C >= 4096) {          // agg chunk >= 24MB, smp fits inside
    agg = (u16*)(ws + off);
    smp = agg;
  } else {
    smp = (u16*)alloc((size_t)NN * DD * 2);
    remain = (ws_size > off) ? (ws_size - off) : 0;
    C = NN;
    while (C > 1024 && (size_t)C * KREL * 2 > remain) C >>= 1;
    agg = (u16*)(ws + off);
  }

  k_invnorm<<<NN / 4, 256, 0, stream>>>(x, invn, H, cur);
  k_prepW<<<(DD * KREL + DD * 768 + 255) / 256, 256, 0, stream>>>(Wrel, Wmp, Wself, WcatT, W2T);
  k_cos<<<EE / 16, 256, 0, stream>>>(H, invn, ei, ety, ncs, we, cur);
  k_scan<<<1, 1024, 0, stream>>>(cur, rp, cur);
  k_scatter<<<EE / 256, 256, 0, stream>>>(ei, ety, we, cur, epack, wsort);

  for (int layer = 0; layer < 2; ++layer) {
    for (int c0 = 0; c0 < NN; c0 += C) {
      k_edge_rel<<<C, 192, 0, stream>>>(H, rp, epack, wsort, agg, sbuf, c0);
      k_gemm<0><<<C / 32, 256, 0, stream>>>(
          agg, nullptr, WcatT, H2 + (size_t)c0 * DD,
          sbuf + (size_t)c0 * 8, brel, nullptr, nullptr, nullptr);
    }
    k_edge_sum<<<NN, 192, 0, stream>>>(H2, rp, epack, smp);
    k_gemm<1><<<NN / 32, 256, 0, stream>>>(
        smp, H2, W2T, H, nullptr, nullptr, bmp, bself, rp);
  }
  k_mean<<<NGR, 192, 0, stream>>>(H, out);
}

// Round 9
// 1161.336 us; speedup vs baseline: 1.0990x; 1.0990x over previous
//
#include <hip/hip_runtime.h>
#include <stdint.h>

typedef unsigned short u16;
typedef unsigned int u32;
typedef __attribute__((ext_vector_type(4))) float f32x4;
typedef __attribute__((ext_vector_type(8))) short bf16x8;

#define NN 32768
#define EE 524288
#define DD 384
#define NREL 8
#define NGR 128
#define KREL (NREL * 384)  // 3072

__device__ __forceinline__ float bf2f(u16 u) {
  union { u32 u; float f; } v; v.u = ((u32)u) << 16; return v.f;
}
__device__ __forceinline__ u16 f2bf(float f) {
  union { float f; u32 u; } v; v.f = f;
  u32 r = v.u + 0x7fffu + ((v.u >> 16) & 1u);
  return (u16)(r >> 16);
}
__device__ __forceinline__ float2 up2(u32 p) {
  return make_float2(bf2f((u16)(p & 0xffffu)), bf2f((u16)(p >> 16)));
}
__device__ __forceinline__ u32 pk2(float a, float b) {
  return (u32)f2bf(a) | ((u32)f2bf(b) << 16);
}
// async 16B global->LDS (LDS dest = wave-uniform base + lane*16)
__device__ __forceinline__ void gl16(const u16* g, char* s) {
  __builtin_amdgcn_global_load_lds(
      (const __attribute__((address_space(1))) unsigned int*)(const void*)g,
      (__attribute__((address_space(3))) unsigned int*)(void*)s, 16, 0, 0);
}
__device__ __forceinline__ float dot4(uint4 a, uint4 b) {
  float2 p, q; float acc;
  p = up2(a.x); q = up2(b.x); acc  = p.x * q.x + p.y * q.y;
  p = up2(a.y); q = up2(b.y); acc += p.x * q.x + p.y * q.y;
  p = up2(a.z); q = up2(b.z); acc += p.x * q.x + p.y * q.y;
  p = up2(a.w); q = up2(b.w); acc += p.x * q.x + p.y * q.y;
  return acc;
}

// ---- per-node: invn = 1/|x|, H = bf16(x) ; zero cur ----
__global__ __launch_bounds__(256) void k_invnorm(const float* __restrict__ x,
                                                 float* __restrict__ invn,
                                                 u16* __restrict__ h0,
                                                 int* __restrict__ cur) {
  const int gid = blockIdx.x * 256 + threadIdx.x;
  if (gid < NN) cur[gid] = 0;
  const int node = gid >> 6;
  const int l = threadIdx.x & 63;
  const float* row = x + (size_t)node * DD;
  float v[6];
  float s = 0.f;
#pragma unroll
  for (int j = 0; j < 6; ++j) { v[j] = row[l + 64 * j]; s += v[j] * v[j]; }
#pragma unroll
  for (int off = 32; off > 0; off >>= 1) s += __shfl_xor(s, off, 64);
  if (l == 0) invn[node] = rsqrtf(s);
  u16* hr = h0 + (size_t)node * DD;
#pragma unroll
  for (int j = 0; j < 6; ++j) hr[l + 64 * j] = f2bf(v[j]);
}

// ---- weight transpose + bf16 convert ----
// WcatT[n][k] (384 x 3072) = W_rel flat[k*384 + n]
// W2T[j][k]   (384 x 768)  = k<384 ? W_mp[k][j] : W_self[k-384][j]
__global__ void k_prepW(const float* __restrict__ Wrel, const float* __restrict__ Wmp,
                        const float* __restrict__ Wself,
                        u16* __restrict__ WcatT, u16* __restrict__ W2T) {
  const int i = blockIdx.x * 256 + threadIdx.x;
  const int total1 = DD * KREL;
  const int total2 = DD * 768;
  if (i < total1) {
    const int n = i / KREL, k = i % KREL;
    WcatT[i] = f2bf(Wrel[(size_t)k * DD + n]);
  } else if (i < total1 + total2) {
    const int ii = i - total1;
    const int j = ii / 768, k = ii % 768;
    const float v = (k < DD) ? Wmp[k * DD + j] : Wself[(k - DD) * DD + j];
    W2T[ii] = f2bf(v);
  }
}

// ---- per-edge weight: 16 lanes/edge + fused hist ----
__global__ __launch_bounds__(256) void k_cos(const u16* __restrict__ H,
                                             const float* __restrict__ invn,
                                             const int* __restrict__ ei,
                                             const int* __restrict__ ety,
                                             const float* __restrict__ ncs,
                                             float* __restrict__ we,
                                             int* __restrict__ cnt) {
  const int e = (int)((blockIdx.x * 256 + threadIdx.x) >> 4);
  const int sub = threadIdx.x & 15;
  const int s = ei[e], d = ei[EE + e];
  const uint4* rs = (const uint4*)(H + (size_t)s * DD);
  const uint4* rd = (const uint4*)(H + (size_t)d * DD);
  float acc = 0.f;
#pragma unroll
  for (int j = 0; j < 3; ++j) acc += dot4(rs[sub + 16 * j], rd[sub + 16 * j]);
#pragma unroll
  for (int m = 1; m < 16; m <<= 1) acc += __shfl_xor(acc, m, 64);
  if (sub == 0) {
    we[e] = acc * invn[s] * invn[d] / ncs[ety[e]];
    atomicAdd(&cnt[d], 1);
  }
}

// single block, 1024 threads: exclusive scan of 32768 degrees
__global__ __launch_bounds__(1024) void k_scan(const int* __restrict__ deg,
                                               int* __restrict__ rp,
                                               int* __restrict__ cur) {
  __shared__ int ps[1024];
  const int t = threadIdx.x;
  const int base = t * 32;
  int loc[32];
  int tot = 0;
#pragma unroll
  for (int j = 0; j < 32; ++j) { loc[j] = tot; tot += deg[base + j]; }
  ps[t] = tot;
  __syncthreads();
  for (int off = 1; off < 1024; off <<= 1) {
    const int v = (t >= off) ? ps[t - off] : 0;
    __syncthreads();
    ps[t] += v;
    __syncthreads();
  }
  const int myoff = ps[t] - tot;  // exclusive
#pragma unroll
  for (int j = 0; j < 32; ++j) {
    const int val = myoff + loc[j];
    rp[base + j] = val;
    cur[base + j] = val;
  }
  if (t == 1023) rp[NN] = EE;
}

__global__ void k_scatter(const int* __restrict__ ei, const int* __restrict__ etype,
                          const float* __restrict__ we, int* __restrict__ cur,
                          int* __restrict__ epack, float* __restrict__ wsort) {
  const int e = blockIdx.x * 256 + threadIdx.x;
  const int d = ei[EE + e];
  const int pos = atomicAdd(&cur[d], 1);
  epack[pos] = ei[e] | (etype[e] << 16);
  wsort[pos] = we[e];
}

// ---- relation-aware aggregation for nodes [base, base+gridDim) ----
__global__ __launch_bounds__(192) void k_edge_rel(
    const u16* __restrict__ H, const int* __restrict__ rp,
    const int* __restrict__ epack, const float* __restrict__ wsort,
    u16* __restrict__ agg, float* __restrict__ sbuf, int base) {
  const int i = base + blockIdx.x;
  const int t = threadIdx.x;
  const int e0 = rp[i], e1 = rp[i + 1];
  float2 a0 = {0, 0}, a1 = {0, 0}, a2 = {0, 0}, a3 = {0, 0};
  float2 a4 = {0, 0}, a5 = {0, 0}, a6 = {0, 0}, a7 = {0, 0};
  float s0 = 0, s1 = 0, s2 = 0, s3 = 0, s4 = 0, s5 = 0, s6 = 0, s7 = 0;
  for (int e = e0; e < e1; ++e) {
    const int pk = epack[e];
    const float w = wsort[e];
    const int src = pk & 0xffff;
    const int ty = pk >> 16;
    const float2 hv = up2(*(const u32*)(H + (size_t)src * DD + 2 * t));
    const float vx = w * hv.x, vy = w * hv.y;
    switch (ty) {
      case 0: a0.x += vx; a0.y += vy; if (t == 0) s0 += w; break;
      case 1: a1.x += vx; a1.y += vy; if (t == 0) s1 += w; break;
      case 2: a2.x += vx; a2.y += vy; if (t == 0) s2 += w; break;
      case 3: a3.x += vx; a3.y += vy; if (t == 0) s3 += w; break;
      case 4: a4.x += vx; a4.y += vy; if (t == 0) s4 += w; break;
      case 5: a5.x += vx; a5.y += vy; if (t == 0) s5 += w; break;
      case 6: a6.x += vx; a6.y += vy; if (t == 0) s6 += w; break;
      default: a7.x += vx; a7.y += vy; if (t == 0) s7 += w; break;
    }
  }
  u32* ap = (u32*)(agg + (size_t)blockIdx.x * KREL);
  ap[0 * 192 + t] = pk2(a0.x, a0.y);
  ap[1 * 192 + t] = pk2(a1.x, a1.y);
  ap[2 * 192 + t] = pk2(a2.x, a2.y);
  ap[3 * 192 + t] = pk2(a3.x, a3.y);
  ap[4 * 192 + t] = pk2(a4.x, a4.y);
  ap[5 * 192 + t] = pk2(a5.x, a5.y);
  ap[6 * 192 + t] = pk2(a6.x, a6.y);
  ap[7 * 192 + t] = pk2(a7.x, a7.y);
  if (t == 0) {
    float* sp = sbuf + (size_t)i * 8;
    sp[0] = s0; sp[1] = s1; sp[2] = s2; sp[3] = s3;
    sp[4] = s4; sp[5] = s5; sp[6] = s6; sp[7] = s7;
  }
}

// ---- unweighted gather-sum: smp[i] = sum_e H2[src] ----
__global__ __launch_bounds__(192) void k_edge_sum(
    const u16* __restrict__ H2, const int* __restrict__ rp,
    const int* __restrict__ epack, u16* __restrict__ smp) {
  const int i = blockIdx.x, t = threadIdx.x;
  const int e0 = rp[i], e1 = rp[i + 1];
  float ax = 0.f, ay = 0.f;
  for (int e = e0; e < e1; ++e) {
    const int src = epack[e] & 0xffff;
    const float2 hv = up2(*(const u32*)(H2 + (size_t)src * DD + 2 * t));
    ax += hv.x; ay += hv.y;
  }
  *(u32*)(smp + (size_t)i * DD + 2 * t) = pk2(ax, ay);
}

// ---- rel-GEMM (R7-measured best): 64x128 tile, 512 thr / 8 waves (wave 32x32),
// XOR-swizzled LDS, XCD-aware 1D block mapping, global_load_lds staging.
// grid = 3 * (M/64); K=3072, A=agg (chunk rows); o = bf16(relu(C + s@b_rel))
__global__ __launch_bounds__(512) void k_gemm0(
    const u16* __restrict__ A0, const u16* __restrict__ Bt,
    u16* __restrict__ o_bf, const float* __restrict__ sbuf,
    const float* __restrict__ brel) {
  constexpr int K = KREL;
  constexpr int AS = KREL;
  __shared__ __align__(16) u16 As[64 * 64];    // 8 KB
  __shared__ __align__(16) u16 Bs[128 * 64];   // 16 KB
  const int tid = threadIdx.x;
  const int w = tid >> 6, l = tid & 63;
  const int per = gridDim.x >> 3;       // blocks per XCD
  const int rpx = per / 3;              // row-tiles per XCD
  const int xcd = blockIdx.x & 7;
  const int idx = blockIdx.x >> 3;
  const int mb = (xcd * rpx + idx / 3) * 64;
  const int nb = (idx % 3) * 128;
  const int arow = tid >> 3;                              // 0..63
  const int swz16 = ((tid & 7) ^ ((tid >> 3) & 7)) * 8;   // logical u16 col
  char* asd = (char*)As + tid * 16;
  char* bsd0 = (char*)Bs + tid * 16;
  char* bsd1 = (char*)Bs + 8192 + tid * 16;
  const int wm = w >> 2;        // 0..1
  const int wn = w & 3;         // 0..3
  const int lr = l & 15;
  const int cb = l >> 4;        // 0..3
  const int sx = l & 7;
  f32x4 acc[2][2] = {};
  const u16* bg = Bt + (size_t)(nb + arow) * K + swz16;
  const size_t b64 = (size_t)64 * K;
  for (int k0 = 0; k0 < K; k0 += 64) {
    gl16(A0 + (size_t)(mb + arow) * AS + k0 + swz16, asd);
    gl16(bg + k0, bsd0);
    gl16(bg + k0 + b64, bsd1);
    __syncthreads();
#pragma unroll
    for (int kk = 0; kk < 64; kk += 32) {
      const int cs = (((kk >> 3) + cb) ^ sx) << 4;
      bf16x8 af[2], bfr[2];
#pragma unroll
      for (int m = 0; m < 2; ++m)
        af[m] = *(const bf16x8*)((const char*)As + (wm * 32 + m * 16 + lr) * 128 + cs);
#pragma unroll
      for (int n = 0; n < 2; ++n)
        bfr[n] = *(const bf16x8*)((const char*)Bs + (wn * 32 + n * 16 + lr) * 128 + cs);
#pragma unroll
      for (int m = 0; m < 2; ++m)
#pragma unroll
        for (int n = 0; n < 2; ++n)
          acc[m][n] = __builtin_amdgcn_mfma_f32_16x16x32_bf16(af[m], bfr[n], acc[m][n], 0, 0, 0);
    }
    __syncthreads();
  }
  const int lg = l >> 4;
#pragma unroll
  for (int n = 0; n < 2; ++n) {
    const int col = nb + wn * 32 + n * 16 + lr;
    float bcol[8];
#pragma unroll
    for (int r = 0; r < 8; ++r) bcol[r] = brel[r * DD + col];
#pragma unroll
    for (int m = 0; m < 2; ++m) {
#pragma unroll
      for (int q = 0; q < 4; ++q) {
        const int row = mb + wm * 32 + m * 16 + lg * 4 + q;
        float v = acc[m][n][q];
        const float* sp = sbuf + (size_t)row * 8;
        float bias = 0.f;
#pragma unroll
        for (int r = 0; r < 8; ++r) bias += sp[r] * bcol[r];
        v = fmaxf(v + bias, 0.f);
        o_bf[(size_t)row * DD + col] = f2bf(v);
      }
    }
  }
}

// ---- mp-GEMM (R6-measured shape + R7-verified swizzle + XCD grouping):
// 128x128 tile, 256 thr / 4 waves, BK=64, K=768.
// A=[smp | H2] (stride 384, split k=384); o = bf16(relu(C + deg*b_mp + b_self))
// grid = 3 * (NN/128) = 768 (1D, XCD-grouped: col-tiles of a row-tile co-located)
__global__ __launch_bounds__(256) void k_gemm1(
    const u16* __restrict__ A0, const u16* __restrict__ A1,
    const u16* __restrict__ Bt, u16* __restrict__ o_bf,
    const float* __restrict__ bmp, const float* __restrict__ bself,
    const int* __restrict__ rp) {
  constexpr int K = 768;
  constexpr int AS = DD;
  __shared__ __align__(16) u16 As[128 * 64];
  __shared__ __align__(16) u16 Bs[128 * 64];
  const int tid = threadIdx.x;
  const int w = tid >> 6, l = tid & 63;
  const int per = gridDim.x >> 3;       // 96
  const int rpx = per / 3;              // 32 row-tiles per XCD
  const int xcd = blockIdx.x & 7;
  const int idx = blockIdx.x >> 3;
  const int mb = (xcd * rpx + idx / 3) * 128;
  const int nb = (idx % 3) * 128;
  const int wr = (w >> 1) * 64;
  const int wc = (w & 1) * 64;
  const int sr = tid >> 3;                          // 0..31
  const int swz16 = ((l & 7) ^ (l >> 3)) * 8;       // pre-swizzled u16 col
  const int lr = l & 15;
  const int cb = l >> 4;
  const int sx = l & 7;
  char* asb = (char*)As;
  char* bsb = (char*)Bs;
  const int wb = w * 1024;
  f32x4 acc[4][4] = {};
  const u16* b0 = Bt + (size_t)(nb + sr) * K + swz16;
  const size_t br32 = (size_t)32 * K;
  const size_t ar32 = (size_t)32 * AS;
  for (int k0 = 0; k0 < K; k0 += 64) {
    const u16* Ab; int ak;
    if (k0 >= DD) { Ab = A1; ak = k0 - DD; }
    else { Ab = A0; ak = k0; }
    const u16* ap = Ab + (size_t)(mb + sr) * AS + ak + swz16;
    gl16(ap,            asb + wb);
    gl16(ap + ar32,     asb + wb + 4096);
    gl16(ap + 2 * ar32, asb + wb + 8192);
    gl16(ap + 3 * ar32, asb + wb + 12288);
    gl16(b0 + k0,            bsb + wb);
    gl16(b0 + k0 + br32,     bsb + wb + 4096);
    gl16(b0 + k0 + 2 * br32, bsb + wb + 8192);
    gl16(b0 + k0 + 3 * br32, bsb + wb + 12288);
    __syncthreads();
#pragma unroll
    for (int kk = 0; kk < 64; kk += 32) {
      const int cs = (((kk >> 3) + cb) ^ sx) << 4;
      bf16x8 af[4], bfr[4];
#pragma unroll
      for (int m = 0; m < 4; ++m)
        af[m] = *(const bf16x8*)((const char*)As + (wr + m * 16 + lr) * 128 + cs);
#pragma unroll
      for (int n = 0; n < 4; ++n)
        bfr[n] = *(const bf16x8*)((const char*)Bs + (wc + n * 16 + lr) * 128 + cs);
#pragma unroll
      for (int m = 0; m < 4; ++m)
#pragma unroll
        for (int n = 0; n < 4; ++n)
          acc[m][n] = __builtin_amdgcn_mfma_f32_16x16x32_bf16(af[m], bfr[n], acc[m][n], 0, 0, 0);
    }
    __syncthreads();
  }
  const int lg = l >> 4;
#pragma unroll
  for (int n = 0; n < 4; ++n) {
    const int col = nb + wc + n * 16 + lr;
    const float bb = bmp[col];
    const float bs = bself[col];
#pragma unroll
    for (int m = 0; m < 4; ++m) {
#pragma unroll
      for (int q = 0; q < 4; ++q) {
        const int row = mb + wr + m * 16 + lg * 4 + q;
        float v = acc[m][n][q];
        const float deg = (float)(rp[row + 1] - rp[row]);
        v = fmaxf(v + deg * bb + bs, 0.f);
        o_bf[(size_t)row * DD + col] = f2bf(v);
      }
    }
  }
}

// ---- mean over 256 nodes per graph ----
__global__ __launch_bounds__(192) void k_mean(const u16* __restrict__ H,
                                              float* __restrict__ out) {
  const int g = blockIdx.x, t = threadIdx.x;
  float ax = 0.f, ay = 0.f;
  const u16* base = H + (size_t)g * 256 * DD;
  for (int j = 0; j < 256; ++j) {
    const float2 hv = up2(*(const u32*)(base + (size_t)j * DD + 2 * t));
    ax += hv.x; ay += hv.y;
  }
  out[g * DD + 2 * t]     = ax * (1.f / 256.f);
  out[g * DD + 2 * t + 1] = ay * (1.f / 256.f);
}

extern "C" void kernel_launch(void* const* d_in, const int* in_sizes, int n_in,
                              void* d_out, int out_size, void* d_ws, size_t ws_size,
                              hipStream_t stream) {
  const float* x     = (const float*)d_in[0];
  const int*   ei    = (const int*)d_in[1];
  const int*   ety   = (const int*)d_in[2];
  const float* Wrel  = (const float*)d_in[4];
  const float* brel  = (const float*)d_in[5];
  const float* ncs   = (const float*)d_in[6];
  const float* Wmp   = (const float*)d_in[7];
  const float* bmp   = (const float*)d_in[8];
  const float* Wself = (const float*)d_in[9];
  const float* bself = (const float*)d_in[10];
  float* out = (float*)d_out;
  (void)in_sizes; (void)n_in; (void)out_size;

  char* ws = (char*)d_ws;
  size_t off = 0;
  auto alloc = [&](size_t bytes) {
    void* p = ws + off;
    off = (off + bytes + 255) & ~(size_t)255;
    return p;
  };
  float* invn  = (float*)alloc((size_t)NN * 4);
  int*   rp    = (int*)alloc(((size_t)NN + 1) * 4);
  int*   cur   = (int*)alloc((size_t)NN * 4);
  float* sbuf  = (float*)alloc((size_t)NN * 8 * 4);
  float* we    = (float*)alloc((size_t)EE * 4);
  int*   epack = (int*)alloc((size_t)EE * 4);
  float* wsort = (float*)alloc((size_t)EE * 4);
  u16*   WcatT = (u16*)alloc((size_t)DD * KREL * 2);
  u16*   W2T   = (u16*)alloc((size_t)DD * 768 * 2);
  u16*   H     = (u16*)alloc((size_t)NN * DD * 2);
  u16*   H2    = (u16*)alloc((size_t)NN * DD * 2);
  // agg chunk sized adaptively; smp aliased into agg's region when it fits
  size_t remain = (ws_size > off) ? (ws_size - off) : 0;
  int C = NN;
  while (C > 1024 && (size_t)C * KREL * 2 > remain) C >>= 1;
  u16* agg;
  u16* smp;
  if (C >= 4096) {          // agg chunk >= 24MB, smp fits inside
    agg = (u16*)(ws + off);
    smp = agg;
  } else {
    smp = (u16*)alloc((size_t)NN * DD * 2);
    remain = (ws_size > off) ? (ws_size - off) : 0;
    C = NN;
    while (C > 1024 && (size_t)C * KREL * 2 > remain) C >>= 1;
    agg = (u16*)(ws + off);
  }

  k_invnorm<<<NN / 4, 256, 0, stream>>>(x, invn, H, cur);
  k_prepW<<<(DD * KREL + DD * 768 + 255) / 256, 256, 0, stream>>>(Wrel, Wmp, Wself, WcatT, W2T);
  k_cos<<<EE / 16, 256, 0, stream>>>(H, invn, ei, ety, ncs, we, cur);
  k_scan<<<1, 1024, 0, stream>>>(cur, rp, cur);
  k_scatter<<<EE / 256, 256, 0, stream>>>(ei, ety, we, cur, epack, wsort);

  for (int layer = 0; layer < 2; ++layer) {
    for (int c0 = 0; c0 < NN; c0 += C) {
      k_edge_rel<<<C, 192, 0, stream>>>(H, rp, epack, wsort, agg, sbuf, c0);
      k_gemm0<<<3 * C / 64, 512, 0, stream>>>(
          agg, WcatT, H2 + (size_t)c0 * DD, sbuf + (size_t)c0 * 8, brel);
    }
    k_edge_sum<<<NN, 192, 0, stream>>>(H2, rp, epack, smp);
    k_gemm1<<<3 * NN / 128, 256, 0, stream>>>(
        smp, H2, W2T, H, bmp, bself, rp);
  }
  k_mean<<<NGR, 192, 0, stream>>>(H, out);
}

// Round 10
// 1039.431 us; speedup vs baseline: 1.2279x; 1.1173x over previous
//
#include <hip/hip_runtime.h>
#include <stdint.h>

typedef unsigned short u16;
typedef unsigned int u32;
typedef __attribute__((ext_vector_type(4))) float f32x4;
typedef __attribute__((ext_vector_type(8))) short bf16x8;

#define NN 32768
#define EE 524288
#define DD 384
#define NREL 8
#define NGR 128
#define KREL (NREL * 384)  // 3072

__device__ __forceinline__ float bf2f(u16 u) {
  union { u32 u; float f; } v; v.u = ((u32)u) << 16; return v.f;
}
__device__ __forceinline__ u16 f2bf(float f) {
  union { float f; u32 u; } v; v.f = f;
  u32 r = v.u + 0x7fffu + ((v.u >> 16) & 1u);
  return (u16)(r >> 16);
}
__device__ __forceinline__ float2 up2(u32 p) {
  return make_float2(bf2f((u16)(p & 0xffffu)), bf2f((u16)(p >> 16)));
}
__device__ __forceinline__ u32 pk2(float a, float b) {
  return (u32)f2bf(a) | ((u32)f2bf(b) << 16);
}
// async 16B global->LDS (LDS dest = wave-uniform base + lane*16)
__device__ __forceinline__ void gl16(const u16* g, char* s) {
  __builtin_amdgcn_global_load_lds(
      (const __attribute__((address_space(1))) unsigned int*)(const void*)g,
      (__attribute__((address_space(3))) unsigned int*)(void*)s, 16, 0, 0);
}
__device__ __forceinline__ float dot4(uint4 a, uint4 b) {
  float2 p, q; float acc;
  p = up2(a.x); q = up2(b.x); acc  = p.x * q.x + p.y * q.y;
  p = up2(a.y); q = up2(b.y); acc += p.x * q.x + p.y * q.y;
  p = up2(a.z); q = up2(b.z); acc += p.x * q.x + p.y * q.y;
  p = up2(a.w); q = up2(b.w); acc += p.x * q.x + p.y * q.y;
  return acc;
}

// ---- per-node: invn = 1/|x|, H = bf16(x) ; zero cur ----
__global__ __launch_bounds__(256) void k_invnorm(const float* __restrict__ x,
                                                 float* __restrict__ invn,
                                                 u16* __restrict__ h0,
                                                 int* __restrict__ cur) {
  const int gid = blockIdx.x * 256 + threadIdx.x;
  if (gid < NN) cur[gid] = 0;
  const int node = gid >> 6;
  const int l = threadIdx.x & 63;
  const float* row = x + (size_t)node * DD;
  float v[6];
  float s = 0.f;
#pragma unroll
  for (int j = 0; j < 6; ++j) { v[j] = row[l + 64 * j]; s += v[j] * v[j]; }
#pragma unroll
  for (int off = 32; off > 0; off >>= 1) s += __shfl_xor(s, off, 64);
  if (l == 0) invn[node] = rsqrtf(s);
  u16* hr = h0 + (size_t)node * DD;
#pragma unroll
  for (int j = 0; j < 6; ++j) hr[l + 64 * j] = f2bf(v[j]);
}

// ---- weight transpose + bf16 convert ----
// WcatT[n][k] (384 x 3072) = W_rel flat[k*384 + n]
// W2T[j][k]   (384 x 768)  = k<384 ? W_mp[k][j] : W_self[k-384][j]
__global__ void k_prepW(const float* __restrict__ Wrel, const float* __restrict__ Wmp,
                        const float* __restrict__ Wself,
                        u16* __restrict__ WcatT, u16* __restrict__ W2T) {
  const int i = blockIdx.x * 256 + threadIdx.x;
  const int total1 = DD * KREL;
  const int total2 = DD * 768;
  if (i < total1) {
    const int n = i / KREL, k = i % KREL;
    WcatT[i] = f2bf(Wrel[(size_t)k * DD + n]);
  } else if (i < total1 + total2) {
    const int ii = i - total1;
    const int j = ii / 768, k = ii % 768;
    const float v = (k < DD) ? Wmp[k * DD + j] : Wself[(k - DD) * DD + j];
    W2T[ii] = f2bf(v);
  }
}

// ---- per-edge weight: 16 lanes/edge + fused hist ----
__global__ __launch_bounds__(256) void k_cos(const u16* __restrict__ H,
                                             const float* __restrict__ invn,
                                             const int* __restrict__ ei,
                                             const int* __restrict__ ety,
                                             const float* __restrict__ ncs,
                                             float* __restrict__ we,
                                             int* __restrict__ cnt) {
  const int e = (int)((blockIdx.x * 256 + threadIdx.x) >> 4);
  const int sub = threadIdx.x & 15;
  const int s = ei[e], d = ei[EE + e];
  const uint4* rs = (const uint4*)(H + (size_t)s * DD);
  const uint4* rd = (const uint4*)(H + (size_t)d * DD);
  float acc = 0.f;
#pragma unroll
  for (int j = 0; j < 3; ++j) acc += dot4(rs[sub + 16 * j], rd[sub + 16 * j]);
#pragma unroll
  for (int m = 1; m < 16; m <<= 1) acc += __shfl_xor(acc, m, 64);
  if (sub == 0) {
    we[e] = acc * invn[s] * invn[d] / ncs[ety[e]];
    atomicAdd(&cnt[d], 1);
  }
}

// single block, 1024 threads: exclusive scan of 32768 degrees
__global__ __launch_bounds__(1024) void k_scan(const int* __restrict__ deg,
                                               int* __restrict__ rp,
                                               int* __restrict__ cur) {
  __shared__ int ps[1024];
  const int t = threadIdx.x;
  const int base = t * 32;
  int loc[32];
  int tot = 0;
#pragma unroll
  for (int j = 0; j < 32; ++j) { loc[j] = tot; tot += deg[base + j]; }
  ps[t] = tot;
  __syncthreads();
  for (int off = 1; off < 1024; off <<= 1) {
    const int v = (t >= off) ? ps[t - off] : 0;
    __syncthreads();
    ps[t] += v;
    __syncthreads();
  }
  const int myoff = ps[t] - tot;  // exclusive
#pragma unroll
  for (int j = 0; j < 32; ++j) {
    const int val = myoff + loc[j];
    rp[base + j] = val;
    cur[base + j] = val;
  }
  if (t == 1023) rp[NN] = EE;
}

__global__ void k_scatter(const int* __restrict__ ei, const int* __restrict__ etype,
                          const float* __restrict__ we, int* __restrict__ cur,
                          int* __restrict__ epack, float* __restrict__ wsort) {
  const int e = blockIdx.x * 256 + threadIdx.x;
  const int d = ei[EE + e];
  const int pos = atomicAdd(&cur[d], 1);
  epack[pos] = ei[e] | (etype[e] << 16);
  wsort[pos] = we[e];
}

// ---- relation-aware aggregation for nodes [base, base+gridDim) ----
__global__ __launch_bounds__(192) void k_edge_rel(
    const u16* __restrict__ H, const int* __restrict__ rp,
    const int* __restrict__ epack, const float* __restrict__ wsort,
    u16* __restrict__ agg, float* __restrict__ sbuf, int base) {
  const int i = base + blockIdx.x;
  const int t = threadIdx.x;
  const int e0 = rp[i], e1 = rp[i + 1];
  float2 a0 = {0, 0}, a1 = {0, 0}, a2 = {0, 0}, a3 = {0, 0};
  float2 a4 = {0, 0}, a5 = {0, 0}, a6 = {0, 0}, a7 = {0, 0};
  float s0 = 0, s1 = 0, s2 = 0, s3 = 0, s4 = 0, s5 = 0, s6 = 0, s7 = 0;
  for (int e = e0; e < e1; ++e) {
    const int pk = epack[e];
    const float w = wsort[e];
    const int src = pk & 0xffff;
    const int ty = pk >> 16;
    const float2 hv = up2(*(const u32*)(H + (size_t)src * DD + 2 * t));
    const float vx = w * hv.x, vy = w * hv.y;
    switch (ty) {
      case 0: a0.x += vx; a0.y += vy; if (t == 0) s0 += w; break;
      case 1: a1.x += vx; a1.y += vy; if (t == 0) s1 += w; break;
      case 2: a2.x += vx; a2.y += vy; if (t == 0) s2 += w; break;
      case 3: a3.x += vx; a3.y += vy; if (t == 0) s3 += w; break;
      case 4: a4.x += vx; a4.y += vy; if (t == 0) s4 += w; break;
      case 5: a5.x += vx; a5.y += vy; if (t == 0) s5 += w; break;
      case 6: a6.x += vx; a6.y += vy; if (t == 0) s6 += w; break;
      default: a7.x += vx; a7.y += vy; if (t == 0) s7 += w; break;
    }
  }
  u32* ap = (u32*)(agg + (size_t)blockIdx.x * KREL);
  ap[0 * 192 + t] = pk2(a0.x, a0.y);
  ap[1 * 192 + t] = pk2(a1.x, a1.y);
  ap[2 * 192 + t] = pk2(a2.x, a2.y);
  ap[3 * 192 + t] = pk2(a3.x, a3.y);
  ap[4 * 192 + t] = pk2(a4.x, a4.y);
  ap[5 * 192 + t] = pk2(a5.x, a5.y);
  ap[6 * 192 + t] = pk2(a6.x, a6.y);
  ap[7 * 192 + t] = pk2(a7.x, a7.y);
  if (t == 0) {
    float* sp = sbuf + (size_t)i * 8;
    sp[0] = s0; sp[1] = s1; sp[2] = s2; sp[3] = s3;
    sp[4] = s4; sp[5] = s5; sp[6] = s6; sp[7] = s7;
  }
}

// ---- unweighted gather-sum: smp[i] = sum_e H2[src] ----
__global__ __launch_bounds__(192) void k_edge_sum(
    const u16* __restrict__ H2, const int* __restrict__ rp,
    const int* __restrict__ epack, u16* __restrict__ smp) {
  const int i = blockIdx.x, t = threadIdx.x;
  const int e0 = rp[i], e1 = rp[i + 1];
  float ax = 0.f, ay = 0.f;
  for (int e = e0; e < e1; ++e) {
    const int src = epack[e] & 0xffff;
    const float2 hv = up2(*(const u32*)(H2 + (size_t)src * DD + 2 * t));
    ax += hv.x; ay += hv.y;
  }
  *(u32*)(smp + (size_t)i * DD + 2 * t) = pk2(ax, ay);
}

// ---- bf16 MFMA GEMM (m97 128x128/4-wave structure + R7-verified swizzle +
// XCD-aware 1D col-grouped grid). BK=64, global_load_lds staging.
// grid = 3 * (M/128), 1D; per XCD contiguous row-tiles, col-tiles co-located.
// MODE 0: K=3072, A=A0 (agg, chunk-local rows); o = bf16(relu(C + s@b_rel))
// MODE 1: K=768,  A=[A0=smp | A1=H2] (stride 384, split k=384), rows global;
//         o = bf16(relu(C + deg*b_mp + b_self))
template <int MODE>
__global__ __launch_bounds__(256) void k_gemm(
    const u16* __restrict__ A0, const u16* __restrict__ A1,
    const u16* __restrict__ Bt, u16* __restrict__ o_bf,
    const float* __restrict__ sbuf, const float* __restrict__ brel,
    const float* __restrict__ bmp, const float* __restrict__ bself,
    const int* __restrict__ rp) {
  constexpr int K = (MODE == 0) ? KREL : 768;
  constexpr int AS = (MODE == 0) ? KREL : DD;  // A row stride
  __shared__ __align__(16) u16 As[128 * 64];
  __shared__ __align__(16) u16 Bs[128 * 64];
  const int tid = threadIdx.x;
  const int w = tid >> 6, l = tid & 63;
  const int per = gridDim.x >> 3;       // blocks per XCD
  const int rpx = per / 3;              // row-tiles per XCD
  const int xcd = blockIdx.x & 7;
  const int idx = blockIdx.x >> 3;
  const int mb = (xcd * rpx + idx / 3) * 128;
  const int nb = (idx % 3) * 128;
  const int wr = (w >> 1) * 64;
  const int wc = (w & 1) * 64;
  const int sr = tid >> 3;                          // 0..31
  const int swz16 = ((l & 7) ^ (l >> 3)) * 8;       // pre-swizzled u16 col
  const int lr = l & 15;
  const int cb = l >> 4;
  const int sx = l & 7;
  char* asb = (char*)As;
  char* bsb = (char*)Bs;
  const int wb = w * 1024;
  f32x4 acc[4][4] = {};
  const u16* b0 = Bt + (size_t)(nb + sr) * K + swz16;
  const size_t br32 = (size_t)32 * K;
  const size_t ar32 = (size_t)32 * AS;
  for (int k0 = 0; k0 < K; k0 += 64) {
    const u16* Ab; int ak;
    if (MODE == 1 && k0 >= DD) { Ab = A1; ak = k0 - DD; }
    else { Ab = A0; ak = k0; }
    const u16* ap = Ab + (size_t)(mb + sr) * AS + ak + swz16;
    gl16(ap,            asb + wb);
    gl16(ap + ar32,     asb + wb + 4096);
    gl16(ap + 2 * ar32, asb + wb + 8192);
    gl16(ap + 3 * ar32, asb + wb + 12288);
    gl16(b0 + k0,            bsb + wb);
    gl16(b0 + k0 + br32,     bsb + wb + 4096);
    gl16(b0 + k0 + 2 * br32, bsb + wb + 8192);
    gl16(b0 + k0 + 3 * br32, bsb + wb + 12288);
    __syncthreads();
#pragma unroll
    for (int kk = 0; kk < 64; kk += 32) {
      const int cs = (((kk >> 3) + cb) ^ sx) << 4;
      bf16x8 af[4], bfr[4];
#pragma unroll
      for (int m = 0; m < 4; ++m)
        af[m] = *(const bf16x8*)((const char*)As + (wr + m * 16 + lr) * 128 + cs);
#pragma unroll
      for (int n = 0; n < 4; ++n)
        bfr[n] = *(const bf16x8*)((const char*)Bs + (wc + n * 16 + lr) * 128 + cs);
#pragma unroll
      for (int m = 0; m < 4; ++m)
#pragma unroll
        for (int n = 0; n < 4; ++n)
          acc[m][n] = __builtin_amdgcn_mfma_f32_16x16x32_bf16(af[m], bfr[n], acc[m][n], 0, 0, 0);
    }
    __syncthreads();
  }
  const int lg = l >> 4;
#pragma unroll
  for (int n = 0; n < 4; ++n) {
    const int col = nb + wc + n * 16 + lr;
    float bcol[8];
    float bb = 0.f, bs = 0.f;
    if (MODE == 0) {
#pragma unroll
      for (int r = 0; r < 8; ++r) bcol[r] = brel[r * DD + col];
    } else {
      bb = bmp[col];
      bs = bself[col];
    }
#pragma unroll
    for (int m = 0; m < 4; ++m) {
#pragma unroll
      for (int q = 0; q < 4; ++q) {
        const int row = mb + wr + m * 16 + lg * 4 + q;
        float v = acc[m][n][q];
        if (MODE == 0) {
          const float* sp = sbuf + (size_t)row * 8;
          float bias = 0.f;
#pragma unroll
          for (int r = 0; r < 8; ++r) bias += sp[r] * bcol[r];
          v = fmaxf(v + bias, 0.f);
        } else {
          const float deg = (float)(rp[row + 1] - rp[row]);
          v = fmaxf(v + deg * bb + bs, 0.f);
        }
        o_bf[(size_t)row * DD + col] = f2bf(v);
      }
    }
  }
}

// ---- mean over 256 nodes per graph ----
__global__ __launch_bounds__(192) void k_mean(const u16* __restrict__ H,
                                              float* __restrict__ out) {
  const int g = blockIdx.x, t = threadIdx.x;
  float ax = 0.f, ay = 0.f;
  const u16* base = H + (size_t)g * 256 * DD;
  for (int j = 0; j < 256; ++j) {
    const float2 hv = up2(*(const u32*)(base + (size_t)j * DD + 2 * t));
    ax += hv.x; ay += hv.y;
  }
  out[g * DD + 2 * t]     = ax * (1.f / 256.f);
  out[g * DD + 2 * t + 1] = ay * (1.f / 256.f);
}

extern "C" void kernel_launch(void* const* d_in, const int* in_sizes, int n_in,
                              void* d_out, int out_size, void* d_ws, size_t ws_size,
                              hipStream_t stream) {
  const float* x     = (const float*)d_in[0];
  const int*   ei    = (const int*)d_in[1];
  const int*   ety   = (const int*)d_in[2];
  const float* Wrel  = (const float*)d_in[4];
  const float* brel  = (const float*)d_in[5];
  const float* ncs   = (const float*)d_in[6];
  const float* Wmp   = (const float*)d_in[7];
  const float* bmp   = (const float*)d_in[8];
  const float* Wself = (const float*)d_in[9];
  const float* bself = (const float*)d_in[10];
  float* out = (float*)d_out;
  (void)in_sizes; (void)n_in; (void)out_size;

  char* ws = (char*)d_ws;
  size_t off = 0;
  auto alloc = [&](size_t bytes) {
    void* p = ws + off;
    off = (off + bytes + 255) & ~(size_t)255;
    return p;
  };
  float* invn  = (float*)alloc((size_t)NN * 4);
  int*   rp    = (int*)alloc(((size_t)NN + 1) * 4);
  int*   cur   = (int*)alloc((size_t)NN * 4);
  float* sbuf  = (float*)alloc((size_t)NN * 8 * 4);
  float* we    = (float*)alloc((size_t)EE * 4);
  int*   epack = (int*)alloc((size_t)EE * 4);
  float* wsort = (float*)alloc((size_t)EE * 4);
  u16*   WcatT = (u16*)alloc((size_t)DD * KREL * 2);
  u16*   W2T   = (u16*)alloc((size_t)DD * 768 * 2);
  u16*   H     = (u16*)alloc((size_t)NN * DD * 2);
  u16*   H2    = (u16*)alloc((size_t)NN * DD * 2);
  // agg chunk sized adaptively; smp aliased into agg's region when it fits
  size_t remain = (ws_size > off) ? (ws_size - off) : 0;
  int C = NN;
  while (C > 1024 && (size_t)C * KREL * 2 > remain) C >>= 1;
  u16* agg;
  u16* smp;
  if (C >= 4096) {          // agg chunk >= 24MB, smp fits inside
    agg = (u16*)(ws + off);
    smp = agg;
  } else {
    smp = (u16*)alloc((size_t)NN * DD * 2);
    remain = (ws_size > off) ? (ws_size - off) : 0;
    C = NN;
    while (C > 1024 && (size_t)C * KREL * 2 > remain) C >>= 1;
    agg = (u16*)(ws + off);
  }

  k_invnorm<<<NN / 4, 256, 0, stream>>>(x, invn, H, cur);
  k_prepW<<<(DD * KREL + DD * 768 + 255) / 256, 256, 0, stream>>>(Wrel, Wmp, Wself, WcatT, W2T);
  k_cos<<<EE / 16, 256, 0, stream>>>(H, invn, ei, ety, ncs, we, cur);
  k_scan<<<1, 1024, 0, stream>>>(cur, rp, cur);
  k_scatter<<<EE / 256, 256, 0, stream>>>(ei, ety, we, cur, epack, wsort);

  for (int layer = 0; layer < 2; ++layer) {
    for (int c0 = 0; c0 < NN; c0 += C) {
      k_edge_rel<<<C, 192, 0, stream>>>(H, rp, epack, wsort, agg, sbuf, c0);
      k_gemm<0><<<3 * C / 128, 256, 0, stream>>>(
          agg, nullptr, WcatT, H2 + (size_t)c0 * DD,
          sbuf + (size_t)c0 * 8, brel, nullptr, nullptr, nullptr);
    }
    k_edge_sum<<<NN, 192, 0, stream>>>(H2, rp, epack, smp);
    k_gemm<1><<<3 * NN / 128, 256, 0, stream>>>(
        smp, H2, W2T, H, nullptr, nullptr, bmp, bself, rp);
  }
  k_mean<<<NGR, 192, 0, stream>>>(H, out);
}